// Round 1
// baseline (1317.159 us; speedup 1.0000x reference)
//
#include <hip/hip_runtime.h>

#define BB 32
#define SS 512
#define EE 512
#define NHH 2
#define HDD 256
#define E3 1536
#define NT 24
#define MR (BB*SS)   // 16384

// =====================================================================
// GEMM: C[M][N] = A[M][K] . B[N][K]^T + bias[N], optional ReLU.
// 128x128 block tile, 256 threads, 8x8 per thread, BK=16.
// =====================================================================
__global__ __launch_bounds__(256) void gemm_bt128(
    const float* __restrict__ A, const float* __restrict__ Bm,
    const float* __restrict__ bias, float* __restrict__ C,
    int M, int N, int K, int relu)
{
    __shared__ __align__(16) float As[16][128];
    __shared__ __align__(16) float Bs[16][128];
    const int t  = threadIdx.x;
    const int mt = blockIdx.y * 128;
    const int nt = blockIdx.x * 128;
    const int tr = t >> 4;          // 0..15
    const int tc = t & 15;          // 0..15
    const int lr = t >> 2;          // 0..63
    const int lk = (t & 3) * 4;     // 0,4,8,12

    float acc[8][8];
#pragma unroll
    for (int i = 0; i < 8; ++i)
#pragma unroll
        for (int j = 0; j < 8; ++j) acc[i][j] = 0.f;

    for (int k0 = 0; k0 < K; k0 += 16) {
        float4 a0 = *(const float4*)(A  + (size_t)(mt + lr)      * K + k0 + lk);
        float4 a1 = *(const float4*)(A  + (size_t)(mt + lr + 64) * K + k0 + lk);
        float4 b0 = *(const float4*)(Bm + (size_t)(nt + lr)      * K + k0 + lk);
        float4 b1 = *(const float4*)(Bm + (size_t)(nt + lr + 64) * K + k0 + lk);
        __syncthreads();
        As[lk+0][lr]    = a0.x; As[lk+1][lr]    = a0.y; As[lk+2][lr]    = a0.z; As[lk+3][lr]    = a0.w;
        As[lk+0][lr+64] = a1.x; As[lk+1][lr+64] = a1.y; As[lk+2][lr+64] = a1.z; As[lk+3][lr+64] = a1.w;
        Bs[lk+0][lr]    = b0.x; Bs[lk+1][lr]    = b0.y; Bs[lk+2][lr]    = b0.z; Bs[lk+3][lr]    = b0.w;
        Bs[lk+0][lr+64] = b1.x; Bs[lk+1][lr+64] = b1.y; Bs[lk+2][lr+64] = b1.z; Bs[lk+3][lr+64] = b1.w;
        __syncthreads();
#pragma unroll
        for (int kk = 0; kk < 16; ++kk) {
            float4 aA = *(const float4*)&As[kk][tr*8];
            float4 aB = *(const float4*)&As[kk][tr*8+4];
            float4 bA = *(const float4*)&Bs[kk][tc*8];
            float4 bB = *(const float4*)&Bs[kk][tc*8+4];
            float av[8] = {aA.x,aA.y,aA.z,aA.w,aB.x,aB.y,aB.z,aB.w};
            float bv[8] = {bA.x,bA.y,bA.z,bA.w,bB.x,bB.y,bB.z,bB.w};
#pragma unroll
            for (int i = 0; i < 8; ++i)
#pragma unroll
                for (int j = 0; j < 8; ++j)
                    acc[i][j] = fmaf(av[i], bv[j], acc[i][j]);
        }
    }
#pragma unroll
    for (int i = 0; i < 8; ++i) {
        const int row = mt + tr*8 + i;
#pragma unroll
        for (int jq = 0; jq < 2; ++jq) {
            const int col = nt + tc*8 + jq*4;
            float4 v;
            v.x = acc[i][jq*4+0] + bias[col+0];
            v.y = acc[i][jq*4+1] + bias[col+1];
            v.z = acc[i][jq*4+2] + bias[col+2];
            v.w = acc[i][jq*4+3] + bias[col+3];
            if (relu) {
                v.x = fmaxf(v.x, 0.f); v.y = fmaxf(v.y, 0.f);
                v.z = fmaxf(v.z, 0.f); v.w = fmaxf(v.w, 0.f);
            }
            *(float4*)(C + (size_t)row * N + col) = v;
        }
    }
}

// =====================================================================
// Attention: one block per (qtile of 16 rows, head, batch). Exact softmax,
// scores (16x512) materialized in LDS. qkv layout: (B*S, 1536) row-major;
// q at +0, k at +512, v at +1024, head h owns channels [h*256, h*256+256).
// Static LDS ~50.6 KB (kept < 64 KB).
// =====================================================================
__global__ __launch_bounds__(256) void attn_kernel(
    const float* __restrict__ qkv, float* __restrict__ attn_out)
{
    const int qt = blockIdx.x;   // 0..31
    const int h  = blockIdx.y;   // 0..1
    const int b  = blockIdx.z;   // 0..31
    const int t  = threadIdx.x;

    __shared__ __align__(16) float Sc[16][516];       // scores, padded
    __shared__ __align__(16) float KV[16*264];        // K^T chunk [8][520] / V tile [16][264]
    __shared__ __align__(16) float Qt[8][20];         // Q^T chunk
    __shared__ float row_sum[16];

    const int q0 = qt * 16;
    const float scale = 0.0625f;  // 1/sqrt(256)

    // ---------------- phase 1: S = Q K^T (raw, unscaled) ----------------
    const int r0 = (t >> 6) * 4;      // 4 rows per wave
    const int c0 = (t & 63) * 8;      // 8 key-cols per thread
    float s[4][8];
#pragma unroll
    for (int i = 0; i < 4; ++i)
#pragma unroll
        for (int j = 0; j < 8; ++j) s[i][j] = 0.f;

    for (int dc = 0; dc < HDD; dc += 8) {
        __syncthreads();
        // stage K^T chunk: KV[dd*520 + c], dd<8, c<512
#pragma unroll
        for (int i = 0; i < 4; ++i) {
            int flat = i * 256 + t;              // 0..1023
            int c  = flat >> 1;                  // 0..511
            int kq = (flat & 1) * 4;             // 0 or 4
            float4 v = *(const float4*)(qkv + (size_t)(b*SS + c)*E3 + EE + h*HDD + dc + kq);
            KV[(kq+0)*520 + c] = v.x;
            KV[(kq+1)*520 + c] = v.y;
            KV[(kq+2)*520 + c] = v.z;
            KV[(kq+3)*520 + c] = v.w;
        }
        // stage Q^T chunk: Qt[dd][r], r<16
        if (t < 32) {
            int r  = t >> 1;
            int kq = (t & 1) * 4;
            float4 v = *(const float4*)(qkv + (size_t)(b*SS + q0 + r)*E3 + h*HDD + dc + kq);
            Qt[kq+0][r] = v.x; Qt[kq+1][r] = v.y; Qt[kq+2][r] = v.z; Qt[kq+3][r] = v.w;
        }
        __syncthreads();
#pragma unroll
        for (int dd = 0; dd < 8; ++dd) {
            float4 q4 = *(const float4*)&Qt[dd][r0];
            float4 kA = *(const float4*)&KV[dd*520 + c0];
            float4 kB = *(const float4*)&KV[dd*520 + c0 + 4];
            float qv[4] = {q4.x, q4.y, q4.z, q4.w};
            float kv[8] = {kA.x,kA.y,kA.z,kA.w,kB.x,kB.y,kB.z,kB.w};
#pragma unroll
            for (int i = 0; i < 4; ++i)
#pragma unroll
                for (int j = 0; j < 8; ++j)
                    s[i][j] = fmaf(qv[i], kv[j], s[i][j]);
        }
    }
    // spill scores to LDS
#pragma unroll
    for (int i = 0; i < 4; ++i) {
        float4 v0 = {s[i][0], s[i][1], s[i][2], s[i][3]};
        float4 v1 = {s[i][4], s[i][5], s[i][6], s[i][7]};
        *(float4*)&Sc[r0+i][c0]   = v0;
        *(float4*)&Sc[r0+i][c0+4] = v1;
    }
    __syncthreads();

    // ---------------- phase 2: softmax rows (in place, unnormalized) -----
    {
        const int r = t >> 4;        // 0..15
        const int j = t & 15;        // 16 threads per row
        const int cbase = j * 32;
        float m = -1e30f;
#pragma unroll
        for (int i = 0; i < 8; ++i) {
            float4 v = *(const float4*)&Sc[r][cbase + i*4];
            m = fmaxf(m, fmaxf(fmaxf(v.x, v.y), fmaxf(v.z, v.w)));
        }
        m = fmaxf(m, __shfl_xor(m, 1, 16));
        m = fmaxf(m, __shfl_xor(m, 2, 16));
        m = fmaxf(m, __shfl_xor(m, 4, 16));
        m = fmaxf(m, __shfl_xor(m, 8, 16));
        float sum = 0.f;
#pragma unroll
        for (int i = 0; i < 8; ++i) {
            float4 v = *(const float4*)&Sc[r][cbase + i*4];
            v.x = __expf((v.x - m) * scale);
            v.y = __expf((v.y - m) * scale);
            v.z = __expf((v.z - m) * scale);
            v.w = __expf((v.w - m) * scale);
            *(float4*)&Sc[r][cbase + i*4] = v;
            sum += v.x + v.y + v.z + v.w;
        }
        sum += __shfl_xor(sum, 1, 16);
        sum += __shfl_xor(sum, 2, 16);
        sum += __shfl_xor(sum, 4, 16);
        sum += __shfl_xor(sum, 8, 16);
        if (j == 0) row_sum[r] = sum;
    }

    // ---------------- phase 3: O = P V ----------------
    const int rr0 = (t >> 5) * 2;     // 0,2,..,14
    const int d0  = (t & 31) * 8;     // 0..248
    float o[2][8];
#pragma unroll
    for (int i = 0; i < 2; ++i)
#pragma unroll
        for (int j = 0; j < 8; ++j) o[i][j] = 0.f;

    for (int vt = 0; vt < 32; ++vt) {
        __syncthreads();   // protects prev-iter KV reads AND (vt==0) Sc/row_sum writes
        // stage V tile: 16 rows x 256 dims
#pragma unroll
        for (int i = 0; i < 4; ++i) {
            int flat = i * 256 + t;            // 0..1023
            int vr = flat >> 6;                // 0..15
            int dq = (flat & 63) * 4;          // 0..252
            float4 v = *(const float4*)(qkv + (size_t)(b*SS + vt*16 + vr)*E3 + 2*EE + h*HDD + dq);
            *(float4*)&KV[vr*264 + dq] = v;
        }
        __syncthreads();
#pragma unroll
        for (int cg = 0; cg < 4; ++cg) {
            float4 p0 = *(const float4*)&Sc[rr0+0][vt*16 + cg*4];
            float4 p1 = *(const float4*)&Sc[rr0+1][vt*16 + cg*4];
            float pa[2][4] = {{p0.x,p0.y,p0.z,p0.w},{p1.x,p1.y,p1.z,p1.w}};
#pragma unroll
            for (int cc = 0; cc < 4; ++cc) {
                float4 vA = *(const float4*)&KV[(cg*4+cc)*264 + d0];
                float4 vB = *(const float4*)&KV[(cg*4+cc)*264 + d0 + 4];
                float vv[8] = {vA.x,vA.y,vA.z,vA.w,vB.x,vB.y,vB.z,vB.w};
#pragma unroll
                for (int i = 0; i < 2; ++i)
#pragma unroll
                    for (int j = 0; j < 8; ++j)
                        o[i][j] = fmaf(pa[i][cc], vv[j], o[i][j]);
            }
        }
    }
    // epilogue: normalize and store
#pragma unroll
    for (int i = 0; i < 2; ++i) {
        float inv = 1.f / row_sum[rr0 + i];
        float4 v0 = {o[i][0]*inv, o[i][1]*inv, o[i][2]*inv, o[i][3]*inv};
        float4 v1 = {o[i][4]*inv, o[i][5]*inv, o[i][6]*inv, o[i][7]*inv};
        size_t base = (size_t)(b*SS + q0 + rr0 + i) * EE + h*HDD + d0;
        *(float4*)(attn_out + base)     = v0;
        *(float4*)(attn_out + base + 4) = v1;
    }
}

// =====================================================================
// CRF emissions: fc[row][j] = dot(dec[row], crf_w[j]) + crf_b[j]
// one thread per (row, tag); 16384*24 threads exactly.
// =====================================================================
__global__ __launch_bounds__(256) void fc_crf_kernel(
    const float* __restrict__ dec, const float* __restrict__ W,
    const float* __restrict__ bias, float* __restrict__ out)
{
    int g = blockIdx.x * 256 + threadIdx.x;
    int row = g / NT;
    int j   = g - row * NT;
    const float4* a = (const float4*)(dec + (size_t)row * EE);
    const float4* w = (const float4*)(W + (size_t)j * EE);
    float acc = 0.f;
#pragma unroll 8
    for (int i = 0; i < 128; ++i) {
        float4 x = a[i], y = w[i];
        acc += x.x*y.x + x.y*y.y + x.z*y.z + x.w*y.w;
    }
    out[g] = acc + bias[j];
}

// =====================================================================
// Segmentation head: log_softmax over 2 classes. One wave per row.
// =====================================================================
__global__ __launch_bounds__(256) void seg_kernel(
    const float* __restrict__ dec, const float* __restrict__ ent_w,
    const float* __restrict__ ent_b, float* __restrict__ segout)
{
    int w    = threadIdx.x >> 6;
    int lane = threadIdx.x & 63;
    int row  = blockIdx.x * 4 + w;
    const float4* a  = (const float4*)(dec + (size_t)row * EE);
    const float4* w0 = (const float4*)(ent_w);
    const float4* w1 = (const float4*)(ent_w + EE);
    float acc0 = 0.f, acc1 = 0.f;
#pragma unroll
    for (int i = 0; i < 2; ++i) {
        int idx = lane * 2 + i;
        float4 x = a[idx];
        float4 u = w0[idx];
        float4 v = w1[idx];
        acc0 += x.x*u.x + x.y*u.y + x.z*u.z + x.w*u.w;
        acc1 += x.x*v.x + x.y*v.y + x.z*v.z + x.w*v.w;
    }
#pragma unroll
    for (int off = 32; off >= 1; off >>= 1) {
        acc0 += __shfl_xor(acc0, off);
        acc1 += __shfl_xor(acc1, off);
    }
    if (lane == 0) {
        float l0 = acc0 + ent_b[0];
        float l1 = acc1 + ent_b[1];
        float m  = fmaxf(l0, l1);
        float lse = m + __logf(__expf(l0 - m) + __expf(l1 - m));
        segout[(size_t)row*2 + 0] = l0 - lse;
        segout[(size_t)row*2 + 1] = l1 - lse;
    }
}

// =====================================================================
// CRF forward + viterbi + numerator, merged (96 blocks, 64 threads).
// mask is all-ones by construction. One block per (role, batch).
// =====================================================================
__global__ __launch_bounds__(64) void crf_all_kernel(
    const float* __restrict__ fc, const int* __restrict__ labels,
    const float* __restrict__ start_t, const float* __restrict__ end_t,
    const float* __restrict__ trans, float* __restrict__ num,
    float* __restrict__ den, float* __restrict__ crf_out)
{
    __shared__ float sc[NT];
    __shared__ float tr[NT*NT];
    __shared__ unsigned char hist[(SS-1)*NT];

    const int role = blockIdx.x >> 5;   // 0=forward, 1=viterbi, 2=numerator
    const int b    = blockIdx.x & 31;
    const int t    = threadIdx.x;

    if (role == 2) {
        // ---- numerator ----
        float acc = 0.f;
        for (int s = 1 + t; s < SS; s += 64) {
            int prev = labels[b*SS + s - 1];
            int cur  = labels[b*SS + s];
            acc += trans[prev*NT + cur] + fc[(size_t)(b*SS + s)*NT + cur];
        }
        if (t == 0) {
            int l0 = labels[b*SS];
            acc += start_t[l0] + fc[(size_t)(b*SS)*NT + l0] + end_t[labels[b*SS + SS - 1]];
        }
#pragma unroll
        for (int off = 32; off >= 1; off >>= 1) acc += __shfl_xor(acc, off);
        if (t == 0) num[b] = acc;
        return;
    }

    for (int i = t; i < NT*NT; i += 64) tr[i] = trans[i];
    if (t < NT) sc[t] = start_t[t] + fc[(size_t)(b*SS)*NT + t];
    __syncthreads();
    const int tj = (t < NT) ? t : 0;

    if (role == 0) {
        // ---- forward (log-normalizer) ----
        for (int s = 1; s < SS; ++s) {
            float em = fc[(size_t)(b*SS + s)*NT + tj];
            float m = sc[0];
#pragma unroll
            for (int i = 1; i < NT; ++i) m = fmaxf(m, sc[i]);
            float sum = 0.f;
#pragma unroll
            for (int i = 0; i < NT; ++i) sum += __expf(sc[i] - m + tr[i*NT + tj]);
            float nxt = m + __logf(sum) + em;
            __syncthreads();
            if (t < NT) sc[t] = nxt;
            __syncthreads();
        }
        float m2 = sc[0] + end_t[0];
#pragma unroll
        for (int i = 1; i < NT; ++i) m2 = fmaxf(m2, sc[i] + end_t[i]);
        float s2 = 0.f;
#pragma unroll
        for (int i = 0; i < NT; ++i) s2 += __expf(sc[i] + end_t[i] - m2);
        if (t == 0) den[b] = m2 + __logf(s2);
    } else {
        // ---- viterbi ----
        for (int s = 1; s < SS; ++s) {
            float em = fc[(size_t)(b*SS + s)*NT + tj];
            float best = sc[0] + tr[tj];
            int arg = 0;
#pragma unroll
            for (int i = 1; i < NT; ++i) {
                float v = sc[i] + tr[i*NT + tj];
                if (v > best) { best = v; arg = i; }
            }
            __syncthreads();
            if (t < NT) { sc[t] = best + em; hist[(s-1)*NT + t] = (unsigned char)arg; }
            __syncthreads();
        }
        if (t == 0) {
            int tag = 0;
            float bv = sc[0] + end_t[0];
            for (int i = 1; i < NT; ++i) {
                float v = sc[i] + end_t[i];
                if (v > bv) { bv = v; tag = i; }
            }
            crf_out[(size_t)b*SS + SS - 1] = (float)tag;
            for (int s = SS - 2; s >= 0; --s) {
                tag = hist[s*NT + tag];
                crf_out[(size_t)b*SS + s] = (float)tag;
            }
        }
    }
}

// =====================================================================
// Final scalar: -llh = -( sum_b(num[b]-den[b]) / 16384 )
// =====================================================================
__global__ __launch_bounds__(64) void llh_kernel(
    const float* __restrict__ num, const float* __restrict__ den,
    float* __restrict__ out)
{
    int t = threadIdx.x;
    float v = (t < BB) ? (num[t] - den[t]) : 0.f;
#pragma unroll
    for (int off = 32; off >= 1; off >>= 1) v += __shfl_xor(v, off);
    if (t == 0) out[(size_t)MR * 3] = -(v / (float)MR);
}

extern "C" void kernel_launch(void* const* d_in, const int* in_sizes, int n_in,
                              void* d_out, int out_size, void* d_ws, size_t ws_size,
                              hipStream_t stream) {
    const float* enc     = (const float*)d_in[0];
    const int*   labels  = (const int*)  d_in[1];
    // d_in[2] = mask (all ones by construction; unused)
    const float* Win     = (const float*)d_in[3];
    const float* bin     = (const float*)d_in[4];
    const float* Wout    = (const float*)d_in[5];
    const float* bout    = (const float*)d_in[6];
    const float* crf_w   = (const float*)d_in[7];
    const float* crf_b   = (const float*)d_in[8];
    const float* start_t = (const float*)d_in[9];
    const float* end_t   = (const float*)d_in[10];
    const float* trans   = (const float*)d_in[11];
    const float* ent_w   = (const float*)d_in[12];
    const float* ent_b   = (const float*)d_in[13];
    float* out = (float*)d_out;

    float* ws   = (float*)d_ws;
    float* qkv  = ws;                                 // 16384*1536
    float* attn = qkv  + (size_t)MR * E3;             // 16384*512
    float* dec  = attn + (size_t)MR * EE;             // 16384*512
    float* fc   = dec  + (size_t)MR * EE;             // 16384*24
    float* num  = fc   + (size_t)MR * NT;             // 32
    float* den  = num  + BB;                          // 32

    dim3 blk(256);
    // 1. qkv = enc @ Win^T + bin
    gemm_bt128<<<dim3(E3/128, MR/128), blk, 0, stream>>>(enc, Win, bin, qkv, MR, E3, EE, 0);
    // 2. attention
    attn_kernel<<<dim3(SS/16, NHH, BB), blk, 0, stream>>>(qkv, attn);
    // 3. dec = relu(attn @ Wout^T + bout)
    gemm_bt128<<<dim3(EE/128, MR/128), blk, 0, stream>>>(attn, Wout, bout, dec, MR, EE, EE, 1);
    // 4. fc emissions
    fc_crf_kernel<<<(MR*NT)/256, blk, 0, stream>>>(dec, crf_w, crf_b, fc);
    // 5. seg head -> d_out[16384 .. 49152)
    seg_kernel<<<MR/4, blk, 0, stream>>>(dec, ent_w, ent_b, out + MR);
    // 6. CRF forward + viterbi + numerator (merged)
    crf_all_kernel<<<96, 64, 0, stream>>>(fc, labels, start_t, end_t, trans, num, den, out);
    // 7. -llh scalar -> d_out[49152]
    llh_kernel<<<1, 64, 0, stream>>>(num, den, out);
}